// Round 1
// baseline (83.712 us; speedup 1.0000x reference)
//
#include <hip/hip_runtime.h>

// out[b,v] = dot(OT[b, pid[v], :], W[v, :]) + bias[v]
// B=32, Q=180, H=768, V=19004. All fp32.
#define BB 32
#define QQ 180
#define HH 768
#define VV 19004
#define CHUNK 16

// ---------- pre-pass: bucket v by q ----------
__global__ void count_k(const int* __restrict__ pid, int* __restrict__ cnt) {
    __shared__ int lc[QQ];
    for (int i = threadIdx.x; i < QQ; i += blockDim.x) lc[i] = 0;
    __syncthreads();
    for (int v = blockIdx.x * blockDim.x + threadIdx.x; v < VV;
         v += gridDim.x * blockDim.x)
        atomicAdd(&lc[pid[v]], 1);
    __syncthreads();
    for (int i = threadIdx.x; i < QQ; i += blockDim.x) {
        int c = lc[i];
        if (c) atomicAdd(&cnt[i], c);
    }
}

__global__ void scan_k(const int* __restrict__ cnt, int* __restrict__ cursor) {
    if (threadIdx.x == 0) {
        int s = 0;
        for (int q = 0; q < QQ; ++q) { cursor[q] = s; s += cnt[q]; }
    }
}

__global__ void scatter_k(const int* __restrict__ pid, int* __restrict__ cursor,
                          int* __restrict__ sorted) {
    for (int v = blockIdx.x * blockDim.x + threadIdx.x; v < VV;
         v += gridDim.x * blockDim.x) {
        int q = pid[v];
        int pos = atomicAdd(&cursor[q], 1);
        sorted[pos] = v;
    }
}

// ---------- main kernel ----------
// Block = 256 threads = 4 waves. Wave w covers b in [8w, 8w+8).
// Lane's h-slice: h = j*256 + lane*4 + k, j=0..2, k=0..3 (float4 coalesced).
// OT[b, q, h-slice] register-cached (96 VGPR/lane), reloaded on q change
// (v's are q-sorted so ~1 reload per block).
__launch_bounds__(256)
__global__ void main_k(const float* __restrict__ OT, const float* __restrict__ W,
                       const float* __restrict__ bias, const int* __restrict__ pid,
                       const int* __restrict__ sorted, float* __restrict__ out) {
    const int lane = threadIdx.x & 63;
    const int wave = threadIdx.x >> 6;
    const int b0 = wave * 8;
    const int base = blockIdx.x * CHUNK;
    const int n = min(CHUNK, VV - base);

    float4 ot[8][3];
    int qcur = -1;

    int v = sorted[base];
    {
    }
    const float* wp = W + (size_t)v * HH + lane * 4;
    float4 w0 = *(const float4*)(wp);
    float4 w1 = *(const float4*)(wp + 256);
    float4 w2 = *(const float4*)(wp + 512);

    for (int i = 0; i < n; ++i) {
        // prefetch next v's W row (hides HBM latency under compute)
        const int vn = sorted[base + ((i + 1 < n) ? (i + 1) : i)];
        const float* wpn = W + (size_t)vn * HH + lane * 4;
        const float4 nw0 = *(const float4*)(wpn);
        const float4 nw1 = *(const float4*)(wpn + 256);
        const float4 nw2 = *(const float4*)(wpn + 512);

        const int q = pid[v];  // wave-uniform
        if (q != qcur) {       // wave-uniform branch
            qcur = q;
#pragma unroll
            for (int b = 0; b < 8; ++b) {
                const float* op =
                    OT + ((size_t)(b0 + b) * QQ + q) * HH + lane * 4;
                ot[b][0] = *(const float4*)(op);
                ot[b][1] = *(const float4*)(op + 256);
                ot[b][2] = *(const float4*)(op + 512);
            }
        }

        float acc[8];
#pragma unroll
        for (int b = 0; b < 8; ++b) {
            float s = w0.x * ot[b][0].x;
            s = fmaf(w0.y, ot[b][0].y, s);
            s = fmaf(w0.z, ot[b][0].z, s);
            s = fmaf(w0.w, ot[b][0].w, s);
            s = fmaf(w1.x, ot[b][1].x, s);
            s = fmaf(w1.y, ot[b][1].y, s);
            s = fmaf(w1.z, ot[b][1].z, s);
            s = fmaf(w1.w, ot[b][1].w, s);
            s = fmaf(w2.x, ot[b][2].x, s);
            s = fmaf(w2.y, ot[b][2].y, s);
            s = fmaf(w2.z, ot[b][2].z, s);
            s = fmaf(w2.w, ot[b][2].w, s);
            acc[b] = s;
        }

        // partial reduce: sum within 8-lane groups for all 8 accs
#pragma unroll
        for (int m = 1; m <= 4; m <<= 1) {
#pragma unroll
            for (int b = 0; b < 8; ++b) acc[b] += __shfl_xor(acc[b], m, 64);
        }
        // each lane picks acc[lane&7] (static cndmask tree, no scratch)
        const bool s0 = lane & 1, s1 = lane & 2, s2 = lane & 4;
        const float c0 = s0 ? acc[1] : acc[0];
        const float c1 = s0 ? acc[3] : acc[2];
        const float c2 = s0 ? acc[5] : acc[4];
        const float c3 = s0 ? acc[7] : acc[6];
        const float d0 = s1 ? c1 : c0;
        const float d1 = s1 ? c3 : c2;
        float val = s2 ? d1 : d0;
        // reduce across the 8 groups
        val += __shfl_xor(val, 8, 64);
        val += __shfl_xor(val, 16, 64);
        val += __shfl_xor(val, 32, 64);

        if (lane < 8) out[(size_t)(b0 + lane) * VV + v] = val + bias[v];

        v = vn;
        w0 = nw0; w1 = nw1; w2 = nw2;
    }
}

extern "C" void kernel_launch(void* const* d_in, const int* in_sizes, int n_in,
                              void* d_out, int out_size, void* d_ws, size_t ws_size,
                              hipStream_t stream) {
    const float* OT   = (const float*)d_in[0];  // [B,Q,H]
    const float* W    = (const float*)d_in[1];  // [V,H]
    const float* bias = (const float*)d_in[2];  // [V]
    const int*   pid  = (const int*)d_in[3];    // [V]
    float* out = (float*)d_out;                 // [B,V]

    int* cnt    = (int*)d_ws;   // 180 used (256 reserved)
    int* cursor = cnt + 256;    // 180 used (256 reserved)
    int* sorted = cnt + 512;    // 19004

    hipMemsetAsync(cnt, 0, QQ * sizeof(int), stream);
    count_k<<<80, 256, 0, stream>>>(pid, cnt);
    scan_k<<<1, 64, 0, stream>>>(cnt, cursor);
    scatter_k<<<80, 256, 0, stream>>>(pid, cursor, sorted);

    const int nb = (VV + CHUNK - 1) / CHUNK;
    main_k<<<nb, 256, 0, stream>>>(OT, W, bias, pid, sorted, out);
}